// Round 4
// baseline (1938.707 us; speedup 1.0000x reference)
//
#include <hip/hip_runtime.h>
#include <stdint.h>

// Problem constants (B=2, T=4096, H=2048, NH=16, HD=128, INTER=8192, K=3)
#define T_DIM 4096
#define H_DIM 2048
#define NHEADS 16
#define HD_DIM 128
#define INTER_DIM 8192
#define B_DIM 2
#define MROWS (B_DIM * T_DIM)   // 8192
#define NCHUNK 32               // T chunking for the scan
#define CHUNK (T_DIM / NCHUNK)  // 128

typedef unsigned short ushort_t;
typedef _Float16 f16x8 __attribute__((ext_vector_type(8)));
typedef __attribute__((ext_vector_type(4))) float f32x4;

__device__ __forceinline__ ushort_t f2h(float f) {
    union { _Float16 h; ushort_t u; } x;
    x.h = (_Float16)f;
    return x.u;
}
__device__ __forceinline__ float h2f(ushort_t u) {
    union { ushort_t u; _Float16 h; } x;
    x.u = u;
    return (float)x.h;
}

// ---- async global->LDS, 16B per lane (dest = wave-uniform base + lane*16)
__device__ __forceinline__ void stage16(const ushort_t* g, ushort_t* lbase) {
#if __has_builtin(__builtin_amdgcn_global_load_lds)
    __builtin_amdgcn_global_load_lds(
        (__attribute__((address_space(1))) unsigned int*)g,
        (__attribute__((address_space(3))) unsigned int*)lbase,
        16, 0, 0);
#else
    ((f16x8*)lbase)[threadIdx.x & 63] = *(const f16x8*)g;
#endif
}

// counted-vmcnt + raw barrier, fused so the compiler cannot move mem ops across
__device__ __forceinline__ void vm8_barrier() {
    asm volatile("s_waitcnt vmcnt(8)\n\ts_barrier" ::: "memory");
}

// =====================================================================
// GEMM256 v4: C[M,N] = A[M,K(lda)] * Bt[N,K(ldb)]^T  (f16 in, f32 acc)
// 256x256 block tile, BK=64, 8 waves (wave = 64-row A stripe x 32-row B
// stripe within each 128-half).
//
// KEY CHANGE vs v3 (which measured MFMA 2640cyc + LDS-read 2300cyc
// SERIALIZED = 5625 cyc/tile): B operand bypasses LDS entirely.
//  - A: global_load_lds staged, double-buffered LDS (64 KiB), 16
//    ds_read_b128/wave/tile (was 24).
//  - B: fragments loaded global->register (plain row-major 16B loads, no
//    swizzle), SINGLE-buffered split-half bf[8], issued one tile ahead at
//    the last use of the old half:
//      MF(0,1) MF(0,0) MF(1,1) [issue bf1(t+1)] MF(1,0) [issue bf0(t+1)]
//    -> ~800+ cyc prefetch gap hides L2 latency, zero extra registers.
//  - ONE barrier per K-tile (A dbuf has no intra-tile hazard), counted
//    vmcnt(8): stage(4) issued first each tile and confirmed at tile end;
//    the 8 bf loads stay in flight across the barrier.
//  - sched_barrier(0) after staging pins the vmcnt ledger order
//    (gl_lds BEFORE bf loads; compiler cannot reorder across it).
// LDS traffic/tile/CU: 32KB W + 128KB R (was 256KB) -> well under MFMA time.
//
// SHIFTS==3: causal-conv mode (A padded (B,T+2,H), per-shift B plane;
// lda==K folds the A shift into a contiguous k walk; B hops plane).
// EPI: 1=f32 out, 2=+bias->f16, 3=+addsrc->f32, 4=silu->f16, 5=plain f16.
// =====================================================================

#define PH_STAGE_A0(W)                                                        \
    if (STG) {                                                                \
        stage16(gAs,          &Asm[(W) * 16384 + wave * 1024]);               \
        stage16(gAs + lda8,   &Asm[(W) * 16384 + wave * 1024 + 512]);         \
    }
#define PH_STAGE_A1(W)                                                        \
    if (STG) {                                                                \
        stage16(gAs + lda128, &Asm[(W) * 16384 + 8192 + wave * 1024]);        \
        stage16(gAs + lda136, &Asm[(W) * 16384 + 8192 + wave * 1024 + 512]);  \
    }

#define LDS_A(R, HA)                                                          \
    _Pragma("unroll")                                                         \
    for (int mi = 0; mi < 4; ++mi) {                                          \
        af[mi * 2 + 0] = *(const f16x8*)&Asm[(R) * 16384 + (HA) * 8192 +      \
                                             mi * 1024 + rdA0];               \
        af[mi * 2 + 1] = *(const f16x8*)&Asm[(R) * 16384 + (HA) * 8192 +      \
                                             mi * 1024 + rdA1];               \
    }

// B fragment loads: global -> regs for stage-target tile ts (one ahead).
// bf[hb*4 + ni*2 + kk] = B[n0 + hb*128 + wn2 + ni*16 + m16][ts*64 + kk*32 + q4*8]
#define BF1_LOAD()                                                            \
    if (STG) {                                                                \
        bf[4] = *(const f16x8*)gB2;                                           \
        bf[5] = *(const f16x8*)(gB2 + 32);                                    \
        bf[6] = *(const f16x8*)gB3;                                           \
        bf[7] = *(const f16x8*)(gB3 + 32);                                    \
    }
#define BF0_LOAD()                                                            \
    if (STG) {                                                                \
        bf[0] = *(const f16x8*)gB0;                                           \
        bf[1] = *(const f16x8*)(gB0 + 32);                                    \
        bf[2] = *(const f16x8*)gB1;                                           \
        bf[3] = *(const f16x8*)(gB1 + 32);                                    \
    }

#define MF(HA, HB)                                                            \
    __builtin_amdgcn_s_setprio(1);                                            \
    _Pragma("unroll")                                                         \
    for (int mi = 0; mi < 4; ++mi)                                            \
    _Pragma("unroll")                                                         \
    for (int ni = 0; ni < 2; ++ni)                                            \
    _Pragma("unroll")                                                         \
    for (int kk = 0; kk < 2; ++kk)                                            \
        acc[(HA) * 4 + mi][(HB) * 2 + ni] =                                   \
            __builtin_amdgcn_mfma_f32_16x16x32_f16(                           \
                af[mi * 2 + kk], bf[(HB) * 4 + ni * 2 + kk],                  \
                acc[(HA) * 4 + mi][(HB) * 2 + ni], 0, 0, 0);                  \
    __builtin_amdgcn_s_setprio(0);

// advance stage pointers to the next stage-target tile (ts)
#define ADVANCE()                                                             \
    {                                                                         \
        gAs += 64;                                                            \
        ++ts;                                                                 \
        if (SHIFTS == 3 && ts < NT && (ts & (KT - 1)) == 0) {                 \
            const ptrdiff_t hop =                                             \
                ((ts == KT) ? (B1 - B0) : (B2 - B1)) -                        \
                (ptrdiff_t)(KT - 1) * 64;                                     \
            gB0 += hop; gB1 += hop; gB2 += hop; gB3 += hop;                   \
        } else {                                                              \
            gB0 += 64; gB1 += 64; gB2 += 64; gB3 += 64;                       \
        }                                                                     \
    }

#define TILE(R, STG_)                                                         \
    {                                                                         \
        const bool STG = STG_;                                                \
        PH_STAGE_A0(1 - (R))                                                  \
        PH_STAGE_A1(1 - (R))                                                  \
        if (STG) __builtin_amdgcn_sched_barrier(0);                           \
        LDS_A(R, 0)                                                           \
        MF(0, 1)                                                              \
        MF(0, 0)                                                              \
        LDS_A(R, 1)                                                           \
        MF(1, 1)                                                              \
        BF1_LOAD()                                                            \
        MF(1, 0)                                                              \
        BF0_LOAD()                                                            \
        if (STG) {                                                            \
            vm8_barrier();                                                    \
            ADVANCE()                                                         \
        }                                                                     \
    }

template <int EPI, int SHIFTS>
__global__ __launch_bounds__(512, 2) void gemm256(
    const ushort_t* __restrict__ A,
    const ushort_t* __restrict__ B0,
    const ushort_t* __restrict__ B1,
    const ushort_t* __restrict__ B2,
    const float* __restrict__ bias,
    const float* addsrc,          // may alias outf (w2 pass 2) - no restrict
    float* outf,
    ushort_t* outb,
    int M, int N, int K, int lda, int ldb)
{
    __shared__ __align__(16) ushort_t Asm[2 * 16384];  // 2 buf x 2 half x 128x64

    const int tid  = threadIdx.x;
    const int lane = tid & 63;
    const int wave = tid >> 6;

    // T1: XCD-aware bijective swizzle (nwg % 8 == 0 for all our grids)
    const int nwg = gridDim.x * gridDim.y;
    const int bid = blockIdx.y * gridDim.x + blockIdx.x;
    const int swz = (bid & 7) * (nwg >> 3) + (bid >> 3);
    const int gxl = 31 - __clz((int)gridDim.x);  // gridDim.x is pow2 (8 or 16)
    const int bx  = swz & ((int)gridDim.x - 1);
    const int by  = swz >> gxl;

    const int m0 = by * 256;
    const int n0 = bx * 256;
    const int wm2 = (wave >> 2) * 64;   // A stripe within each 128-half
    const int wn2 = (wave & 3) * 32;    // B stripe within each 128-half
    const int m16 = lane & 15;
    const int q4  = lane >> 4;
    const int l7  = lane & 7;
    const int srow = lane >> 3;            // staging row within 8-row chunk
    const int soct = (lane & 7) ^ srow;    // XOR swizzle: LDS[r][o] = G[r][o^(r&7)]

    const int KT = K >> 6;        // K-tiles per shift (pow2)
    const int NT = SHIFTS * KT;   // total K-tiles (even)

    // hoisted LDS read bases (ushort indices); kk=1 flips swizzle bit -> ^32
    const int rdA0 = (wm2 + m16) * 64 + (q4 ^ l7) * 8;
    const int rdA1 = rdA0 ^ 32;

    // hoisted global A staging pointers (per-thread, swizzled source)
    const size_t lda8 = (size_t)lda * 8, lda128 = (size_t)lda * 128, lda136 = (size_t)lda * 136;
    const size_t athr = (size_t)(wave * 16 + srow) * lda + soct * 8;
    const ushort_t* gAs;
    if (SHIFTS == 3) {
        int b = m0 >> 12;  // m0 / T_DIM
        gAs = A + (size_t)(m0 + 2 * b) * lda + athr;   // shift 0; lda==K folds shifts
    } else {
        gAs = A + (size_t)m0 * lda + athr;
    }

    // B fragment row pointers (per-lane, natural row-major, no swizzle)
    const ushort_t* gB0 = B0 + (size_t)(n0 + wn2 + m16) * ldb + q4 * 8;
    const ushort_t* gB1 = gB0 + (size_t)16 * ldb;
    const ushort_t* gB2 = gB0 + (size_t)128 * ldb;
    const ushort_t* gB3 = gB0 + (size_t)144 * ldb;
    int ts = 0;  // stage-target tile index

    f32x4 acc[8][4];
#pragma unroll
    for (int i = 0; i < 8; i++)
#pragma unroll
        for (int j = 0; j < 4; j++)
#pragma unroll
            for (int r = 0; r < 4; r++) acc[i][j][r] = 0.f;

    f16x8 af[8];    // current A half frags (mi x kk), from LDS
    f16x8 bf[8];    // B frags both halves (hb x ni x kk), global->reg, 1 tile ahead

    // prologue: stage A(0), load bf(0); vmcnt(8) confirms stage, bf stays in flight
    {
        const bool STG = true;
        PH_STAGE_A0(0)
        PH_STAGE_A1(0)
        __builtin_amdgcn_sched_barrier(0);
        BF1_LOAD()
        BF0_LOAD()
        ADVANCE()   // pointers now at tile 1
    }
    vm8_barrier();

    for (int t = 0; t < NT - 2; t += 2) {
        TILE(0, true)
        TILE(1, true)
    }
    TILE(0, true)    // t = NT-2, stages tile NT-1, loads bf(NT-1)
    TILE(1, false)   // drain tile NT-1

    // epilogue: D row = q4*4 + r within frag, col = lane&15
#pragma unroll
    for (int a = 0; a < 8; ++a) {
        const int ha = a >> 2, mi = a & 3;
#pragma unroll
        for (int b = 0; b < 4; ++b) {
            const int hb = b >> 1, ni = b & 1;
            const int col = n0 + hb * 128 + wn2 + ni * 16 + m16;
#pragma unroll
            for (int r = 0; r < 4; ++r) {
                const int row = m0 + ha * 128 + wm2 + mi * 16 + q4 * 4 + r;
                const size_t idx = (size_t)row * N + col;
                float v = acc[a][b][r];
                if (EPI == 1) {
                    outf[idx] = v;
                } else if (EPI == 2) {
                    outb[idx] = f2h(v + bias[col]);
                } else if (EPI == 3) {
                    outf[idx] = addsrc[idx] + v;
                } else if (EPI == 4) {
                    outb[idx] = f2h(v / (1.f + expf(-v)));
                } else if (EPI == 5) {
                    outb[idx] = f2h(v);
                }
            }
        }
    }
}

#undef PH_STAGE_A0
#undef PH_STAGE_A1
#undef LDS_A
#undef BF1_LOAD
#undef BF0_LOAD
#undef MF
#undef ADVANCE
#undef TILE

// ---- fp32 (R,C) -> fp16 (C,R) transpose, LDS tiled
__global__ void transpose_to_f16(const float* __restrict__ in, ushort_t* __restrict__ out,
                                 int R, int C) {
    __shared__ float tile[32][33];
    int c0 = blockIdx.x * 32, r0 = blockIdx.y * 32;
    int tx = threadIdx.x, ty = threadIdx.y;
#pragma unroll
    for (int j = 0; j < 32; j += 8)
        tile[ty + j][tx] = in[(size_t)(r0 + ty + j) * C + c0 + tx];
    __syncthreads();
#pragma unroll
    for (int j = 0; j < 32; j += 8)
        out[(size_t)(c0 + ty + j) * R + r0 + tx] = f2h(tile[tx][ty + j]);
}

// ---- conv_w (O,I,3) fp32 -> three fp16 planes Wk[o][i] = conv_w[o,i,k]
__global__ void conv_w_convert(const float* __restrict__ cw, ushort_t* __restrict__ w0,
                               ushort_t* __restrict__ w1, ushort_t* __restrict__ w2) {
    int gid = blockIdx.x * 256 + threadIdx.x;  // o*H + i
    const float* p = cw + (size_t)gid * 3;
    w0[gid] = f2h(p[0]);
    w1[gid] = f2h(p[1]);
    w2[gid] = f2h(p[2]);
}

// ---- rmsnorm -> fp16. pad=1: write into (B, T+2, H) layout with 2 zero rows/batch
__global__ __launch_bounds__(256) void rmsnorm_kernel(const float* __restrict__ x,
                                                      const float* __restrict__ w,
                                                      ushort_t* __restrict__ out, int pad) {
    int r = blockIdx.x;
    int tid = threadIdx.x;
    const float* row = x + (size_t)r * H_DIM;
    float xs[8];
    *(float4*)&xs[0] = *(const float4*)&row[tid * 8];
    *(float4*)&xs[4] = *(const float4*)&row[tid * 8 + 4];
    float ss = 0.f;
#pragma unroll
    for (int e = 0; e < 8; e++) ss += xs[e] * xs[e];
#pragma unroll
    for (int o = 32; o >= 1; o >>= 1) ss += __shfl_down(ss, o, 64);
    __shared__ float red[4];
    if ((tid & 63) == 0) red[tid >> 6] = ss;
    __syncthreads();
    float rs = rsqrtf((red[0] + red[1] + red[2] + red[3]) * (1.f / 2048.f) + 1e-6f);
    float ws[8];
    *(float4*)&ws[0] = *(const float4*)&w[tid * 8];
    *(float4*)&ws[4] = *(const float4*)&w[tid * 8 + 4];
    ushort_t* orow;
    if (pad) {
        int b = r >> 12, t = r & 4095;
        orow = out + ((size_t)b * (T_DIM + 2) + 2 + t) * H_DIM;
        if (t == 0) {
            ushort_t* pz = out + (size_t)b * (T_DIM + 2) * H_DIM;
            for (int e = tid; e < 2 * H_DIM; e += 256) pz[e] = 0;
        }
    } else {
        orow = out + (size_t)r * H_DIM;
    }
#pragma unroll
    for (int e = 0; e < 8; e++) orow[tid * 8 + e] = f2h(xs[e] * rs * ws[e]);
}

// ---- dt = softplus(attn_in @ w_dt + b_dt + dt_bias), layout (B*NH, T)
__global__ __launch_bounds__(256) void dt_kernel(const ushort_t* __restrict__ apad,
                                                 const float* __restrict__ wdt,
                                                 const float* __restrict__ bdt,
                                                 const float* __restrict__ dtb,
                                                 float* __restrict__ beta_arr) {
    int r = blockIdx.x;
    int b = r >> 12, t = r & 4095;
    int tid = threadIdx.x, lane = tid & 63, wv = tid >> 6;
    const ushort_t* row = apad + ((size_t)b * (T_DIM + 2) + 2 + t) * H_DIM;
    float acc[16];
#pragma unroll
    for (int nh = 0; nh < 16; nh++) acc[nh] = 0.f;
    f16x8 xv = *(const f16x8*)&row[tid * 8];
#pragma unroll
    for (int e = 0; e < 8; e++) {
        float x = (float)xv[e];
        const float* wrow = wdt + (size_t)(tid * 8 + e) * 16;
#pragma unroll
        for (int nh = 0; nh < 16; nh++) acc[nh] += x * wrow[nh];
    }
    __shared__ float part[4][16];
#pragma unroll
    for (int nh = 0; nh < 16; nh++) {
        float v = acc[nh];
#pragma unroll
        for (int o = 32; o >= 1; o >>= 1) v += __shfl_down(v, o, 64);
        if (lane == 0) part[wv][nh] = v;
    }
    __syncthreads();
    if (tid < 16) {
        float v = part[0][tid] + part[1][tid] + part[2][tid] + part[3][tid];
        float x = v + bdt[tid] + dtb[tid];
        float dt = (x > 20.f) ? x : log1pf(expf(x));
        beta_arr[(size_t)(b * 16 + tid) * T_DIM + t] = dt;
    }
}

// ---- p = exp(cumsum(A*dt)) inclusive; c = beta / (p + eps). one block per (b,nh)
__global__ __launch_bounds__(256) void scan_prep(const float* __restrict__ beta_arr,
                                                 const float* __restrict__ A_log,
                                                 float* __restrict__ p_arr,
                                                 float* __restrict__ c_arr) {
    int bh = blockIdx.x;
    int nh = bh & 15;
    int tid = threadIdx.x;
    float Ac = -expf(A_log[nh]);
    size_t base = (size_t)bh * T_DIM;
    float bet[16], pref[16];
    float run = 0.f;
#pragma unroll
    for (int j = 0; j < 16; j++) {
        bet[j] = beta_arr[base + tid * 16 + j];
        run += Ac * bet[j];
        pref[j] = run;
    }
    __shared__ float red[256];
    red[tid] = run;
    __syncthreads();
    if (tid == 0) {
        float a = 0.f;
        for (int i = 0; i < 256; i++) { float x = red[i]; red[i] = a; a += x; }
    }
    __syncthreads();
    float off = red[tid];
#pragma unroll
    for (int j = 0; j < 16; j++) {
        float p = expf(off + pref[j]);
        p_arr[base + tid * 16 + j] = p;
        c_arr[base + tid * 16 + j] = bet[j] / (p + 1e-6f);
    }
}

// ---- chunked cumsum of c*v: pass 1 partial sums per chunk (v is fp16)
__global__ __launch_bounds__(128) void scan_partial(const float* __restrict__ c_arr,
                                                    const ushort_t* __restrict__ v_buf,
                                                    float* __restrict__ csum) {
    int blk = blockIdx.x;           // bh*NCHUNK + ch
    int ch = blk & (NCHUNK - 1), bh = blk >> 5;
    int b = bh >> 4, nh = bh & 15;
    int tid = threadIdx.x;          // hd
    int t0 = ch * CHUNK;
    __shared__ float cs[CHUNK];
    cs[tid] = c_arr[(size_t)bh * T_DIM + t0 + tid];
    __syncthreads();
    float s = 0.f;
    const ushort_t* vbase = v_buf + ((size_t)(b * T_DIM + t0) * 16 + nh) * 128 + tid;
    for (int tt = 0; tt < CHUNK; tt++) s += cs[tt] * h2f(vbase[(size_t)tt * 2048]);
    csum[(size_t)blk * 128 + tid] = s;
}

// ---- pass 2: exclusive prefix over chunks per channel
__global__ __launch_bounds__(128) void scan_combine(const float* __restrict__ csum,
                                                    float* __restrict__ cpref) {
    int bh = blockIdx.x;
    int tid = threadIdx.x;
    float run = 0.f;
    for (int ch = 0; ch < NCHUNK; ch++) {
        size_t i = ((size_t)bh * NCHUNK + ch) * 128 + tid;
        cpref[i] = run;
        run += csum[i];
    }
}

// ---- pass 3: s = prefix + running cumsum; y = q * (p * s) -> fp16 (q,v fp16)
__global__ __launch_bounds__(128) void scan_final(const float* __restrict__ c_arr,
                                                  const float* __restrict__ p_arr,
                                                  const ushort_t* __restrict__ v_buf,
                                                  const ushort_t* __restrict__ q_buf,
                                                  const float* __restrict__ cpref,
                                                  ushort_t* __restrict__ y_head) {
    int blk = blockIdx.x;
    int ch = blk & (NCHUNK - 1), bh = blk >> 5;
    int b = bh >> 4, nh = bh & 15;
    int tid = threadIdx.x;
    int t0 = ch * CHUNK;
    __shared__ float cs[CHUNK], ps[CHUNK];
    cs[tid] = c_arr[(size_t)bh * T_DIM + t0 + tid];
    ps[tid] = p_arr[(size_t)bh * T_DIM + t0 + tid];
    __syncthreads();
    float s = cpref[(size_t)blk * 128 + tid];
    size_t vb = ((size_t)(b * T_DIM + t0) * 16 + nh) * 128 + tid;
    for (int tt = 0; tt < CHUNK; tt++) {
        size_t vi = vb + (size_t)tt * 2048;
        s += cs[tt] * h2f(v_buf[vi]);
        float y = h2f(q_buf[vi]) * (ps[tt] * s);
        y_head[vi] = f2h(y);
    }
}

// ---- RoPE in-place on q (B*T, NH, HD) fp16
__global__ __launch_bounds__(256) void rope_f16(ushort_t* __restrict__ q,
                                                const int* __restrict__ pos_ids) {
    int gid = blockIdx.x * 256 + threadIdx.x;  // over B*T*NH*64 pairs
    int j = gid & 63;
    int rest = gid >> 6;
    int bt = rest >> 4;
    size_t idx = (size_t)bt * 2048 + (size_t)(rest & 15) * 128 + 2 * j;
    float pos = (float)pos_ids[bt];
    const float LN = 0.14391157f;  // ln(10000)/64
    int d0 = 2 * j, d1 = 2 * j + 1;
    float a0 = pos * expf(-(float)(d0 & 63) * LN);
    float a1 = pos * expf(-(float)(d1 & 63) * LN);
    float q0 = h2f(q[idx]), q1 = h2f(q[idx + 1]);
    q[idx]     = f2h(q0 * cosf(a0) - q1 * sinf(a0));
    q[idx + 1] = f2h(q1 * cosf(a1) + q0 * sinf(a1));
}

// =====================================================================
extern "C" void kernel_launch(void* const* d_in, const int* in_sizes, int n_in,
                              void* d_out, int out_size, void* d_ws, size_t ws_size,
                              hipStream_t stream) {
    (void)in_sizes; (void)n_in; (void)out_size;
    const float* hidden  = (const float*)d_in[0];
    const int*   pos_ids = (const int*)d_in[1];
    const float* conv_w  = (const float*)d_in[2];
    const float* conv_b  = (const float*)d_in[3];
    const float* wq      = (const float*)d_in[4];
    const float* wv      = (const float*)d_in[5];
    const float* w_dt    = (const float*)d_in[6];
    const float* b_dt    = (const float*)d_in[7];
    const float* A_log   = (const float*)d_in[8];
    const float* dt_bias = (const float*)d_in[9];
    const float* wo      = (const float*)d_in[10];
    const float* w1      = (const float*)d_in[11];
    const float* w2      = (const float*)d_in[12];
    const float* n1w     = (const float*)d_in[13];
    const float* n2w     = (const float*)d_in[14];
    float* out = (float*)d_out;

    // -------- static workspace layout with lifetime overlays (bytes) --------
    constexpr size_t MB8 = 8ull * 1024 * 1024;
    constexpr size_t SCAN_SM = 524288;  // beta/parr/carr AND csum/cprf
    constexpr size_t R0   = 0;
    constexpr size_t R0sz = 10 * MB8;                  // 80 MiB
    constexpr size_t R1   = R0 + R0sz;                 // h_buf (f32 64MiB) over qb+vb (f16)
    constexpr size_t R1sz = 8 * MB8;
    constexpr size_t R2   = R1 + R1sz;                 // apad / mlp_in
    constexpr size_t R2sz = (size_t)B_DIM * (T_DIM + 2) * H_DIM * 2;  // 33,570,816
    constexpr size_t R3   = R2 + R2sz;                 // w1_t
    constexpr size_t R3sz = 4 * MB8;
    constexpr size_t R4   = R3 + R3sz;                 // w2_t
    constexpr size_t R4sz = 4 * MB8;
    constexpr size_t R5   = R4 + R4sz;                 // small scan buffers
    constexpr size_t R5sz = 5 * SCAN_SM;
    constexpr size_t NEED = R5 + R5sz;                 // ~242.5 MiB
    if (ws_size < NEED) return;  // clean failure instead of a fault

    char* w = (char*)d_ws;
    ushort_t* wc0    = (ushort_t*)(w + R0 + 0 * MB8);
    ushort_t* wc1    = (ushort_t*)(w + R0 + 1 * MB8);
    ushort_t* wc2    = (ushort_t*)(w + R0 + 2 * MB8);
    ushort_t* wq_t   = (ushort_t*)(w + R0 + 3 * MB8);
    ushort_t* wv_t   = (ushort_t*)(w + R0 + 4 * MB8);
    ushort_t* wo_t   = (ushort_t*)(w + R0 + 5 * MB8);
    ushort_t* xb     = (ushort_t*)(w + R0 + 6 * MB8);  // 32 MiB; also y_head
    ushort_t* a_half = (ushort_t*)(w + R0);            // 64 MiB, written after all above die
    ushort_t* qb     = (ushort_t*)(w + R1);            // f16 32 MiB
    ushort_t* vb     = (ushort_t*)(w + R1 + 4 * MB8);  // f16 32 MiB
    float*    h_buf  = (float*)(w + R1);               // f32 64 MiB, after q/v die
    ushort_t* apad   = (ushort_t*)(w + R2);
    ushort_t* w1_t   = (ushort_t*)(w + R3);
    ushort_t* w2_t   = (ushort_t*)(w + R4);
    float*    beta   = (float*)(w + R5 + 0 * SCAN_SM);
    float*    parr   = (float*)(w + R5 + 1 * SCAN_SM);
    float*    carr   = (float*)(w + R5 + 2 * SCAN_SM);
    float*    csum   = (float*)(w + R5 + 3 * SCAN_SM);
    float*    cprf   = (float*)(w + R5 + 4 * SCAN_SM);
    ushort_t* mlp_in = apad;
    ushort_t* y_head = xb;

    // weight conversions
    conv_w_convert<<<(2048 * 2048) / 256, 256, 0, stream>>>(conv_w, wc0, wc1, wc2);
    transpose_to_f16<<<dim3(64, 64), dim3(32, 8), 0, stream>>>(wq, wq_t, 2048, 2048);
    transpose_to_f16<<<dim3(64, 64), dim3(32, 8), 0, stream>>>(wv, wv_t, 2048, 2048);
    transpose_to_f16<<<dim3(64, 64), dim3(32, 8), 0, stream>>>(wo, wo_t, 2048, 2048);
    transpose_to_f16<<<dim3(256, 64), dim3(32, 8), 0, stream>>>(w1, w1_t, 2048, 8192);
    transpose_to_f16<<<dim3(64, 256), dim3(32, 8), 0, stream>>>(w2, w2_t, 8192, 2048);

    // norm1 -> padded f16 (conv input / dt input)
    rmsnorm_kernel<<<MROWS, 256, 0, stream>>>(hidden, n1w, apad, 1);
    // dt path
    dt_kernel<<<MROWS, 256, 0, stream>>>(apad, w_dt, b_dt, dt_bias, beta);
    scan_prep<<<B_DIM * NHEADS, 256, 0, stream>>>(beta, A_log, parr, carr);

    // conv (3-shift GEMM) -> x f16
    gemm256<2, 3><<<dim3(8, 32), 512, 0, stream>>>(
        apad, wc0, wc1, wc2, conv_b, nullptr, nullptr, xb,
        MROWS, 2048, 2048, 2048, 2048);
    // q, v projections -> f16
    gemm256<5, 1><<<dim3(8, 32), 512, 0, stream>>>(
        xb, wq_t, wq_t, wq_t, nullptr, nullptr, nullptr, qb,
        MROWS, 2048, 2048, 2048, 2048);
    gemm256<5, 1><<<dim3(8, 32), 512, 0, stream>>>(
        xb, wv_t, wv_t, wv_t, nullptr, nullptr, nullptr, vb,
        MROWS, 2048, 2048, 2048, 2048);
    rope_f16<<<(MROWS * NHEADS * 64) / 256, 256, 0, stream>>>(qb, pos_ids);

    // delta-net scan -> y_head f16 (overwrites xb: conv-x dead after q/v)
    scan_partial<<<B_DIM * NHEADS * NCHUNK, 128, 0, stream>>>(carr, vb, csum);
    scan_combine<<<B_DIM * NHEADS, 128, 0, stream>>>(csum, cprf);
    scan_final<<<B_DIM * NHEADS * NCHUNK, 128, 0, stream>>>(carr, parr, vb, qb, cprf, y_head);

    // wo + residual -> h (overwrites qb/vb region: both dead)
    gemm256<3, 1><<<dim3(8, 32), 512, 0, stream>>>(
        y_head, wo_t, wo_t, wo_t, nullptr, hidden, h_buf, nullptr,
        MROWS, 2048, 2048, 2048, 2048);
    // norm2 -> mlp_in f16 (overwrites apad)
    rmsnorm_kernel<<<MROWS, 256, 0, stream>>>(h_buf, n2w, mlp_in, 0);

    // MLP in two INTER/2 halves to halve the intermediate buffer
    for (int ha = 0; ha < 2; ha++) {
        // silu(mlp_in @ w1_half) -> a_half f16
        gemm256<4, 1><<<dim3(16, 32), 512, 0, stream>>>(
            mlp_in, w1_t + (size_t)ha * 4096 * 2048, nullptr, nullptr,
            nullptr, nullptr, nullptr, a_half,
            MROWS, 4096, 2048, 2048, 2048);
        // out = (ha==0 ? h : out) + a_half @ w2_half
        gemm256<3, 1><<<dim3(8, 32), 512, 0, stream>>>(
            a_half, w2_t + (size_t)ha * 4096, nullptr, nullptr,
            nullptr, (ha == 0) ? h_buf : out, out, nullptr,
            MROWS, 2048, 4096, 4096, 8192);
    }
}

// Round 5
// 1632.936 us; speedup vs baseline: 1.1873x; 1.1873x over previous
//
#include <hip/hip_runtime.h>
#include <stdint.h>

// Problem constants (B=2, T=4096, H=2048, NH=16, HD=128, INTER=8192, K=3)
#define T_DIM 4096
#define H_DIM 2048
#define NHEADS 16
#define HD_DIM 128
#define INTER_DIM 8192
#define B_DIM 2
#define MROWS (B_DIM * T_DIM)   // 8192
#define NCHUNK 32               // T chunking for the scan
#define CHUNK (T_DIM / NCHUNK)  // 128

typedef unsigned short ushort_t;
typedef _Float16 f16x8 __attribute__((ext_vector_type(8)));
typedef __attribute__((ext_vector_type(4))) float f32x4;

__device__ __forceinline__ ushort_t f2h(float f) {
    union { _Float16 h; ushort_t u; } x;
    x.h = (_Float16)f;
    return x.u;
}
__device__ __forceinline__ float h2f(ushort_t u) {
    union { ushort_t u; _Float16 h; } x;
    x.u = u;
    return (float)x.h;
}

// ---- async global->LDS, 16B per lane (dest = wave-uniform base + lane*16)
__device__ __forceinline__ void stage16(const ushort_t* g, ushort_t* lbase) {
#if __has_builtin(__builtin_amdgcn_global_load_lds)
    __builtin_amdgcn_global_load_lds(
        (__attribute__((address_space(1))) unsigned int*)g,
        (__attribute__((address_space(3))) unsigned int*)lbase,
        16, 0, 0);
#else
    ((f16x8*)lbase)[threadIdx.x & 63] = *(const f16x8*)g;
#endif
}

__device__ __forceinline__ void barx() { asm volatile("s_barrier" ::: "memory"); }
__device__ __forceinline__ void vm6_bar() {
    asm volatile("s_waitcnt vmcnt(6)\n\ts_barrier" ::: "memory");
}
__device__ __forceinline__ void vm0_bar() {
    asm volatile("s_waitcnt vmcnt(0)\n\ts_barrier" ::: "memory");
}
__device__ __forceinline__ void lgkm0() {
    asm volatile("s_waitcnt lgkmcnt(0)" ::: "memory");
    __builtin_amdgcn_sched_barrier(0);   // rule #18: pin MFMA below the wait
}

// =====================================================================
// GEMM256 v5 = v3 data layout + m201 8-phase schedule (plain-HIP port).
// 256x256 tile, BK=64, 8 waves (wave = 64-row A stripe x 32-row B stripe
// within each 128-half; per-wave output 128x64). LDS 128 KiB: per operand
// 2 buf x [2 half x 128 x 64] f16, octet-XOR swizzled (0-conflict).
//
// Iteration = 2 K-tiles: t (buf0) in ph1-4, t+1 (buf1) in ph5-8.
// Phase = { ds_read quadrant frags | stage 1 half-tile (2 gl_lds) |
//           s_barrier ; lgkmcnt(0)+sched_barrier ; 16 MFMA (setprio) ;
//           s_barrier }.
// Quadrants: ph1/5 (m0,n0) reads Alo(12: 8A+4B), ph2/6 (m0,n1) reads
// Bhi(4), ph3/7 (m1,n0) reads Ahi(8), ph4/8 (m1,n1) reads 0 (regs held).
// Stage rotation (region's last read is >=1 phase + 2 barriers earlier):
//   ph1: Ahi(t+1)  ph2: Alo(t+2)  ph3: Blo(t+2)  ph4: Bhi(t+2)
//   ph5: Ahi(t+2)  ph6: Alo(t+3)  ph7: Blo(t+3)  ph8: Bhi(t+3)
// vmcnt(6) ONLY at ph4/ph8 (3 half-tiles in flight; ledger audited):
//   ph8 confirms tile t+2 fully (needed next-iter ph1-3);
//   ph4 confirms Ahi(t+1)+tile-(t+1) remainder (needed ph5-7).
// Prologue: stage Alo0,Blo0,Bhi0,Ahi0,Alo1,Blo1,Bhi1 then vmcnt(6)+bar.
// Final iteration: stage only ph1 Ahi(NT-1); vmcnt(0) at ph4.
//
// SHIFTS==3: causal-conv mode (A padded (B,T+2,H): lda==K folds the 3
// shifts into one contiguous k-walk; B hops plane at tile multiples of KT).
// EPI: 1=f32 out, 2=+bias->f16, 3=+addsrc->f32, 4=silu->f16, 5=plain f16.
// =====================================================================

#define ST_ALO(W, GA)                                                         \
    {                                                                         \
        stage16((GA),        &Asm[(W) * 16384 + wave * 1024]);                \
        stage16((GA) + lda8, &Asm[(W) * 16384 + wave * 1024 + 512]);          \
    }
#define ST_AHI(W, GA)                                                         \
    {                                                                         \
        stage16((GA) + lda128, &Asm[(W) * 16384 + 8192 + wave * 1024]);       \
        stage16((GA) + lda136, &Asm[(W) * 16384 + 8192 + wave * 1024 + 512]); \
    }
#define ST_BLO(W, GB)                                                         \
    {                                                                         \
        stage16((GB),        &Bsm[(W) * 16384 + wave * 1024]);                \
        stage16((GB) + ldb8, &Bsm[(W) * 16384 + wave * 1024 + 512]);          \
    }
#define ST_BHI(W, GB)                                                         \
    {                                                                         \
        stage16((GB) + ldb128, &Bsm[(W) * 16384 + 8192 + wave * 1024]);       \
        stage16((GB) + ldb136, &Bsm[(W) * 16384 + 8192 + wave * 1024 + 512]); \
    }

#define LDS_A(R, HA)                                                          \
    _Pragma("unroll")                                                         \
    for (int mi = 0; mi < 4; ++mi) {                                          \
        af[mi * 2 + 0] = *(const f16x8*)&Asm[(R) * 16384 + (HA) * 8192 +      \
                                             mi * 1024 + rdA0];               \
        af[mi * 2 + 1] = *(const f16x8*)&Asm[(R) * 16384 + (HA) * 8192 +      \
                                             mi * 1024 + rdA1];               \
    }
#define LDS_B(R, HB)                                                          \
    _Pragma("unroll")                                                         \
    for (int ni = 0; ni < 2; ++ni) {                                          \
        bf[(HB) * 4 + ni * 2 + 0] =                                           \
            *(const f16x8*)&Bsm[(R) * 16384 + (HB) * 8192 + ni * 1024 + rdB0];\
        bf[(HB) * 4 + ni * 2 + 1] =                                           \
            *(const f16x8*)&Bsm[(R) * 16384 + (HB) * 8192 + ni * 1024 + rdB1];\
    }
#define MF(HA, HB)                                                            \
    __builtin_amdgcn_s_setprio(1);                                            \
    _Pragma("unroll")                                                         \
    for (int mi = 0; mi < 4; ++mi)                                            \
    _Pragma("unroll")                                                         \
    for (int ni = 0; ni < 2; ++ni)                                            \
    _Pragma("unroll")                                                         \
    for (int kk = 0; kk < 2; ++kk)                                            \
        acc[(HA) * 4 + mi][(HB) * 2 + ni] =                                   \
            __builtin_amdgcn_mfma_f32_16x16x32_f16(                           \
                af[mi * 2 + kk], bf[(HB) * 4 + ni * 2 + kk],                  \
                acc[(HA) * 4 + mi][(HB) * 2 + ni], 0, 0, 0);                  \
    __builtin_amdgcn_s_setprio(0);

// advance B stage pointer to the next stage-target tile
#define ADV_B()                                                               \
    {                                                                         \
        ++ts;                                                                 \
        if (SHIFTS == 3 && ts < NT && (ts & (KT - 1)) == 0) {                 \
            gB = ((ts == KT) ? gBp1 : gBp2) + (size_t)(ts & (KT - 1)) * 64;   \
            gB += (size_t)(ts - ((ts >= 2 * KT) ? 2 * KT : KT)) * 64;         \
        } else {                                                              \
            gB += 64;                                                         \
        }                                                                     \
    }

#define ITER(STG)                                                             \
    {                                                                         \
        /* ph1: quad (m0,n0) tile t (buf0) */                                 \
        LDS_A(0, 0)                                                           \
        LDS_B(0, 0)                                                           \
        ST_AHI(1, gA)                       /* Ahi(t+1), also in final */     \
        barx(); lgkm0();                                                      \
        MF(0, 0)                                                              \
        barx();                                                               \
        /* ph2: quad (m0,n1) */                                               \
        LDS_B(0, 1)                                                           \
        if (STG) ST_ALO(0, gA + 64)         /* Alo(t+2) */                    \
        barx(); lgkm0();                                                      \
        MF(0, 1)                                                              \
        barx();                                                               \
        /* ph3: quad (m1,n0) */                                               \
        LDS_A(0, 1)                                                           \
        if (STG) ST_BLO(0, gB)              /* Blo(t+2) */                    \
        barx(); lgkm0();                                                      \
        MF(1, 0)                                                              \
        barx();                                                               \
        /* ph4: quad (m1,n1); vmcnt point */                                  \
        if (STG) { ST_BHI(0, gB) vm6_bar(); } else { vm0_bar(); }             \
        lgkm0();                                                              \
        MF(1, 1)                                                              \
        barx();                                                               \
        if (STG) ADV_B()                    /* gB -> t+3 */                   \
        /* ph5: quad (m0,n0) tile t+1 (buf1) */                               \
        LDS_A(1, 0)                                                           \
        LDS_B(1, 0)                                                           \
        if (STG) ST_AHI(0, gA + 64)         /* Ahi(t+2) */                    \
        barx(); lgkm0();                                                      \
        MF(0, 0)                                                              \
        barx();                                                               \
        /* ph6 */                                                             \
        LDS_B(1, 1)                                                           \
        if (STG) ST_ALO(1, gA + 128)        /* Alo(t+3) */                    \
        barx(); lgkm0();                                                      \
        MF(0, 1)                                                              \
        barx();                                                               \
        /* ph7 */                                                             \
        LDS_A(1, 1)                                                           \
        if (STG) ST_BLO(1, gB)              /* Blo(t+3) */                    \
        barx(); lgkm0();                                                      \
        MF(1, 0)                                                              \
        barx();                                                               \
        /* ph8: vmcnt point */                                                \
        if (STG) { ST_BHI(1, gB) vm6_bar(); } else { barx(); }                \
        lgkm0();                                                              \
        MF(1, 1)                                                              \
        barx();                                                               \
        if (STG) { ADV_B() gA += 128; }                                       \
    }

template <int EPI, int SHIFTS>
__global__ __launch_bounds__(512, 2) void gemm256(
    const ushort_t* __restrict__ A,
    const ushort_t* __restrict__ B0,
    const ushort_t* __restrict__ B1,
    const ushort_t* __restrict__ B2,
    const float* __restrict__ bias,
    const float* addsrc,          // may alias outf (w2 pass 2) - no restrict
    float* outf,
    ushort_t* outb,
    int M, int N, int K, int lda, int ldb)
{
    __shared__ __align__(16) ushort_t Asm[2 * 16384];  // 2 buf x 2 half x 128x64
    __shared__ __align__(16) ushort_t Bsm[2 * 16384];

    const int tid  = threadIdx.x;
    const int lane = tid & 63;
    const int wave = tid >> 6;

    // T1: XCD-aware bijective swizzle (nwg % 8 == 0 for all our grids)
    const int nwg = gridDim.x * gridDim.y;
    const int bid = blockIdx.y * gridDim.x + blockIdx.x;
    const int swz = (bid & 7) * (nwg >> 3) + (bid >> 3);
    const int gxl = 31 - __clz((int)gridDim.x);  // gridDim.x is pow2 (8 or 16)
    const int bx  = swz & ((int)gridDim.x - 1);
    const int by  = swz >> gxl;

    const int m0 = by * 256;
    const int n0 = bx * 256;
    const int wm2 = (wave >> 2) * 64;   // A stripe within each 128-half
    const int wn2 = (wave & 3) * 32;    // B stripe within each 128-half
    const int m16 = lane & 15;
    const int q4  = lane >> 4;
    const int l7  = lane & 7;
    const int srow = lane >> 3;            // staging row within 8-row chunk
    const int soct = (lane & 7) ^ srow;    // XOR swizzle: LDS[r][o] = G[r][o^(r&7)]

    const int KT = K >> 6;        // K-tiles per shift (pow2)
    const int NT = SHIFTS * KT;   // total K-tiles (even)
    const int NIT = NT >> 1;      // iterations (2 tiles each)

    // hoisted LDS read bases (ushort indices); kk=1 flips swizzle bit -> ^32
    const int rdA0 = (wm2 + m16) * 64 + (q4 ^ l7) * 8;
    const int rdA1 = rdA0 ^ 32;
    const int rdB0 = (wn2 + m16) * 64 + (q4 ^ l7) * 8;
    const int rdB1 = rdB0 ^ 32;

    // hoisted global staging pointers (per-thread)
    const size_t lda8 = (size_t)lda * 8, lda128 = (size_t)lda * 128, lda136 = (size_t)lda * 136;
    const size_t ldb8 = (size_t)ldb * 8, ldb128 = (size_t)ldb * 128, ldb136 = (size_t)ldb * 136;
    const size_t athr = (size_t)(wave * 16 + srow) * lda + soct * 8;
    const size_t bthr = (size_t)(wave * 16 + srow) * ldb + soct * 8;
    const ushort_t* gA;
    if (SHIFTS == 3) {
        int b = m0 >> 12;  // m0 / T_DIM
        gA = A + (size_t)(m0 + 2 * b) * lda + athr;   // tile 0; lda==K folds shifts
    } else {
        gA = A + (size_t)m0 * lda + athr;
    }
    const ushort_t* gB  = B0 + (size_t)n0 * ldb + bthr;
    const ushort_t* gBp1 = (SHIFTS == 3) ? (B1 + (size_t)n0 * ldb + bthr) : nullptr;
    const ushort_t* gBp2 = (SHIFTS == 3) ? (B2 + (size_t)n0 * ldb + bthr) : nullptr;
    int ts = 0;  // tile index gB points at

    f32x4 acc[8][4];
#pragma unroll
    for (int i = 0; i < 8; i++)
#pragma unroll
        for (int j = 0; j < 4; j++)
#pragma unroll
            for (int r = 0; r < 4; r++) acc[i][j][r] = 0.f;

    f16x8 af[8];    // current A half frags (mi x kk)
    f16x8 bf[8];    // B frags, both n-halves (hb x ni x kk), held across tile

    // ---- prologue: stage 7 halves in ledger order, confirm tile 0 ----
    ST_ALO(0, gA)          // Alo(0)
    ST_BLO(0, gB)          // Blo(0)
    ST_BHI(0, gB)          // Bhi(0)
    ST_AHI(0, gA)          // Ahi(0)
    ST_ALO(1, gA + 64)     // Alo(1)
    ADV_B()                // ts=1
    ST_BLO(1, gB)          // Blo(1)
    ST_BHI(1, gB)          // Bhi(1)
    ADV_B()                // ts=2 (stage target t+2 for it0)
    vm6_bar();             // confirm tile 0 halves; 3 halves in flight
    gA += 64;              // gA -> tile 1 (ph1 stages Ahi(t+1))

    for (int it = 0; it < NIT - 1; ++it) {
        ITER(1)
    }
    ITER(0)   // final: computes NT-2, NT-1; stages only ph1's Ahi(NT-1)

    // epilogue: D row = q4*4 + r within frag, col = lane&15
#pragma unroll
    for (int a = 0; a < 8; ++a) {
        const int ha = a >> 2, mi = a & 3;
#pragma unroll
        for (int b = 0; b < 4; ++b) {
            const int hb = b >> 1, ni = b & 1;
            const int col = n0 + hb * 128 + wn2 + ni * 16 + m16;
#pragma unroll
            for (int r = 0; r < 4; ++r) {
                const int row = m0 + ha * 128 + wm2 + mi * 16 + q4 * 4 + r;
                const size_t idx = (size_t)row * N + col;
                float v = acc[a][b][r];
                if (EPI == 1) {
                    outf[idx] = v;
                } else if (EPI == 2) {
                    outb[idx] = f2h(v + bias[col]);
                } else if (EPI == 3) {
                    outf[idx] = addsrc[idx] + v;
                } else if (EPI == 4) {
                    outb[idx] = f2h(v / (1.f + expf(-v)));
                } else if (EPI == 5) {
                    outb[idx] = f2h(v);
                }
            }
        }
    }
}

#undef ST_ALO
#undef ST_AHI
#undef ST_BLO
#undef ST_BHI
#undef LDS_A
#undef LDS_B
#undef MF
#undef ADV_B
#undef ITER

// ---- fp32 (R,C) -> fp16 (C,R) transpose, LDS tiled
__global__ void transpose_to_f16(const float* __restrict__ in, ushort_t* __restrict__ out,
                                 int R, int C) {
    __shared__ float tile[32][33];
    int c0 = blockIdx.x * 32, r0 = blockIdx.y * 32;
    int tx = threadIdx.x, ty = threadIdx.y;
#pragma unroll
    for (int j = 0; j < 32; j += 8)
        tile[ty + j][tx] = in[(size_t)(r0 + ty + j) * C + c0 + tx];
    __syncthreads();
#pragma unroll
    for (int j = 0; j < 32; j += 8)
        out[(size_t)(c0 + ty + j) * R + r0 + tx] = f2h(tile[tx][ty + j]);
}

// ---- conv_w (O,I,3) fp32 -> three fp16 planes Wk[o][i] = conv_w[o,i,k]
__global__ void conv_w_convert(const float* __restrict__ cw, ushort_t* __restrict__ w0,
                               ushort_t* __restrict__ w1, ushort_t* __restrict__ w2) {
    int gid = blockIdx.x * 256 + threadIdx.x;  // o*H + i
    const float* p = cw + (size_t)gid * 3;
    w0[gid] = f2h(p[0]);
    w1[gid] = f2h(p[1]);
    w2[gid] = f2h(p[2]);
}

// ---- rmsnorm -> fp16. pad=1: write into (B, T+2, H) layout with 2 zero rows/batch
__global__ __launch_bounds__(256) void rmsnorm_kernel(const float* __restrict__ x,
                                                      const float* __restrict__ w,
                                                      ushort_t* __restrict__ out, int pad) {
    int r = blockIdx.x;
    int tid = threadIdx.x;
    const float* row = x + (size_t)r * H_DIM;
    float xs[8];
    *(float4*)&xs[0] = *(const float4*)&row[tid * 8];
    *(float4*)&xs[4] = *(const float4*)&row[tid * 8 + 4];
    float ss = 0.f;
#pragma unroll
    for (int e = 0; e < 8; e++) ss += xs[e] * xs[e];
#pragma unroll
    for (int o = 32; o >= 1; o >>= 1) ss += __shfl_down(ss, o, 64);
    __shared__ float red[4];
    if ((tid & 63) == 0) red[tid >> 6] = ss;
    __syncthreads();
    float rs = rsqrtf((red[0] + red[1] + red[2] + red[3]) * (1.f / 2048.f) + 1e-6f);
    float ws[8];
    *(float4*)&ws[0] = *(const float4*)&w[tid * 8];
    *(float4*)&ws[4] = *(const float4*)&w[tid * 8 + 4];
    ushort_t* orow;
    if (pad) {
        int b = r >> 12, t = r & 4095;
        orow = out + ((size_t)b * (T_DIM + 2) + 2 + t) * H_DIM;
        if (t == 0) {
            ushort_t* pz = out + (size_t)b * (T_DIM + 2) * H_DIM;
            for (int e = tid; e < 2 * H_DIM; e += 256) pz[e] = 0;
        }
    } else {
        orow = out + (size_t)r * H_DIM;
    }
#pragma unroll
    for (int e = 0; e < 8; e++) orow[tid * 8 + e] = f2h(xs[e] * rs * ws[e]);
}

// ---- dt = softplus(attn_in @ w_dt + b_dt + dt_bias), layout (B*NH, T)
__global__ __launch_bounds__(256) void dt_kernel(const ushort_t* __restrict__ apad,
                                                 const float* __restrict__ wdt,
                                                 const float* __restrict__ bdt,
                                                 const float* __restrict__ dtb,
                                                 float* __restrict__ beta_arr) {
    int r = blockIdx.x;
    int b = r >> 12, t = r & 4095;
    int tid = threadIdx.x, lane = tid & 63, wv = tid >> 6;
    const ushort_t* row = apad + ((size_t)b * (T_DIM + 2) + 2 + t) * H_DIM;
    float acc[16];
#pragma unroll
    for (int nh = 0; nh < 16; nh++) acc[nh] = 0.f;
    f16x8 xv = *(const f16x8*)&row[tid * 8];
#pragma unroll
    for (int e = 0; e < 8; e++) {
        float x = (float)xv[e];
        const float* wrow = wdt + (size_t)(tid * 8 + e) * 16;
#pragma unroll
        for (int nh = 0; nh < 16; nh++) acc[nh] += x * wrow[nh];
    }
    __shared__ float part[4][16];
#pragma unroll
    for (int nh = 0; nh < 16; nh++) {
        float v = acc[nh];
#pragma unroll
        for (int o = 32; o >= 1; o >>= 1) v += __shfl_down(v, o, 64);
        if (lane == 0) part[wv][nh] = v;
    }
    __syncthreads();
    if (tid < 16) {
        float v = part[0][tid] + part[1][tid] + part[2][tid] + part[3][tid];
        float x = v + bdt[tid] + dtb[tid];
        float dt = (x > 20.f) ? x : log1pf(expf(x));
        beta_arr[(size_t)(b * 16 + tid) * T_DIM + t] = dt;
    }
}

// ---- p = exp(cumsum(A*dt)) inclusive; c = beta / (p + eps). one block per (b,nh)
__global__ __launch_bounds__(256) void scan_prep(const float* __restrict__ beta_arr,
                                                 const float* __restrict__ A_log,
                                                 float* __restrict__ p_arr,
                                                 float* __restrict__ c_arr) {
    int bh = blockIdx.x;
    int nh = bh & 15;
    int tid = threadIdx.x;
    float Ac = -expf(A_log[nh]);
    size_t base = (size_t)bh * T_DIM;
    float bet[16], pref[16];
    float run = 0.f;
#pragma unroll
    for (int j = 0; j < 16; j++) {
        bet[j] = beta_arr[base + tid * 16 + j];
        run += Ac * bet[j];
        pref[j] = run;
    }
    __shared__ float red[256];
    red[tid] = run;
    __syncthreads();
    if (tid == 0) {
        float a = 0.f;
        for (int i = 0; i < 256; i++) { float x = red[i]; red[i] = a; a += x; }
    }
    __syncthreads();
    float off = red[tid];
#pragma unroll
    for (int j = 0; j < 16; j++) {
        float p = expf(off + pref[j]);
        p_arr[base + tid * 16 + j] = p;
        c_arr[base + tid * 16 + j] = bet[j] / (p + 1e-6f);
    }
}

// ---- chunked cumsum of c*v: pass 1 partial sums per chunk (v is fp16)
__global__ __launch_bounds__(128) void scan_partial(const float* __restrict__ c_arr,
                                                    const ushort_t* __restrict__ v_buf,
                                                    float* __restrict__ csum) {
    int blk = blockIdx.x;           // bh*NCHUNK + ch
    int ch = blk & (NCHUNK - 1), bh = blk >> 5;
    int b = bh >> 4, nh = bh & 15;
    int tid = threadIdx.x;          // hd
    int t0 = ch * CHUNK;
    __shared__ float cs[CHUNK];
    cs[tid] = c_arr[(size_t)bh * T_DIM + t0 + tid];
    __syncthreads();
    float s = 0.f;
    const ushort_t* vbase = v_buf + ((size_t)(b * T_DIM + t0) * 16 + nh) * 128 + tid;
    for (int tt = 0; tt < CHUNK; tt++) s += cs[tt] * h2f(vbase[(size_t)tt * 2048]);
    csum[(size_t)blk * 128 + tid] = s;
}

// ---- pass 2: exclusive prefix over chunks per channel
__global__ __launch_bounds__(128) void scan_combine(const float* __restrict__ csum,
                                                    float* __restrict__ cpref) {
    int bh = blockIdx.x;
    int tid = threadIdx.x;
    float run = 0.f;
    for (int ch = 0; ch < NCHUNK; ch++) {
        size_t i = ((size_t)bh * NCHUNK + ch) * 128 + tid;
        cpref[i] = run;
        run += csum[i];
    }
}

// ---- pass 3: s = prefix + running cumsum; y = q * (p * s) -> fp16 (q,v fp16)
__global__ __launch_bounds__(128) void scan_final(const float* __restrict__ c_arr,
                                                  const float* __restrict__ p_arr,
                                                  const ushort_t* __restrict__ v_buf,
                                                  const ushort_t* __restrict__ q_buf,
                                                  const float* __restrict__ cpref,
                                                  ushort_t* __restrict__ y_head) {
    int blk = blockIdx.x;
    int ch = blk & (NCHUNK - 1), bh = blk >> 5;
    int b = bh >> 4, nh = bh & 15;
    int tid = threadIdx.x;
    int t0 = ch * CHUNK;
    __shared__ float cs[CHUNK], ps[CHUNK];
    cs[tid] = c_arr[(size_t)bh * T_DIM + t0 + tid];
    ps[tid] = p_arr[(size_t)bh * T_DIM + t0 + tid];
    __syncthreads();
    float s = cpref[(size_t)blk * 128 + tid];
    size_t vb = ((size_t)(b * T_DIM + t0) * 16 + nh) * 128 + tid;
    for (int tt = 0; tt < CHUNK; tt++) {
        size_t vi = vb + (size_t)tt * 2048;
        s += cs[tt] * h2f(v_buf[vi]);
        float y = h2f(q_buf[vi]) * (ps[tt] * s);
        y_head[vi] = f2h(y);
    }
}

// ---- RoPE in-place on q (B*T, NH, HD) fp16
__global__ __launch_bounds__(256) void rope_f16(ushort_t* __restrict__ q,
                                                const int* __restrict__ pos_ids) {
    int gid = blockIdx.x * 256 + threadIdx.x;  // over B*T*NH*64 pairs
    int j = gid & 63;
    int rest = gid >> 6;
    int bt = rest >> 4;
    size_t idx = (size_t)bt * 2048 + (size_t)(rest & 15) * 128 + 2 * j;
    float pos = (float)pos_ids[bt];
    const float LN = 0.14391157f;  // ln(10000)/64
    int d0 = 2 * j, d1 = 2 * j + 1;
    float a0 = pos * expf(-(float)(d0 & 63) * LN);
    float a1 = pos * expf(-(float)(d1 & 63) * LN);
    float q0 = h2f(q[idx]), q1 = h2f(q[idx + 1]);
    q[idx]     = f2h(q0 * cosf(a0) - q1 * sinf(a0));
    q[idx + 1] = f2h(q1 * cosf(a1) + q0 * sinf(a1));
}

// =====================================================================
extern "C" void kernel_launch(void* const* d_in, const int* in_sizes, int n_in,
                              void* d_out, int out_size, void* d_ws, size_t ws_size,
                              hipStream_t stream) {
    (void)in_sizes; (void)n_in; (void)out_size;
    const float* hidden  = (const float*)d_in[0];
    const int*   pos_ids = (const int*)d_in[1];
    const float* conv_w  = (const float*)d_in[2];
    const float* conv_b  = (const float*)d_in[3];
    const float* wq      = (const float*)d_in[4];
    const float* wv      = (const float*)d_in[5];
    const float* w_dt    = (const float*)d_in[6];
    const float* b_dt    = (const float*)d_in[7];
    const float* A_log   = (const float*)d_in[8];
    const float* dt_bias = (const float*)d_in[9];
    const float* wo      = (const float*)d_in[10];
    const float* w1      = (const float*)d_in[11];
    const float* w2      = (const float*)d_in[12];
    const float* n1w     = (const float*)d_in[13];
    const float* n2w     = (const float*)d_in[14];
    float* out = (float*)d_out;

    // -------- static workspace layout with lifetime overlays (bytes) --------
    constexpr size_t MB8 = 8ull * 1024 * 1024;
    constexpr size_t SCAN_SM = 524288;  // beta/parr/carr AND csum/cprf
    constexpr size_t R0   = 0;
    constexpr size_t R0sz = 10 * MB8;                  // 80 MiB
    constexpr size_t R1   = R0 + R0sz;                 // h_buf (f32 64MiB) over qb+vb (f16)
    constexpr size_t R1sz = 8 * MB8;
    constexpr size_t R2   = R1 + R1sz;                 // apad / mlp_in
    constexpr size_t R2sz = (size_t)B_DIM * (T_DIM + 2) * H_DIM * 2;  // 33,570,816
    constexpr size_t R3   = R2 + R2sz;                 // w1_t
    constexpr size_t R3sz = 4 * MB8;
    constexpr size_t R4   = R3 + R3sz;                 // w2_t
    constexpr size_t R4sz = 4 * MB8;
    constexpr size_t R5   = R4 + R4sz;                 // small scan buffers
    constexpr size_t R5sz = 5 * SCAN_SM;
    constexpr size_t NEED = R5 + R5sz;                 // ~242.5 MiB
    if (ws_size < NEED) return;  // clean failure instead of a fault

    char* w = (char*)d_ws;
    ushort_t* wc0    = (ushort_t*)(w + R0 + 0 * MB8);
    ushort_t* wc1    = (ushort_t*)(w + R0 + 1 * MB8);
    ushort_t* wc2    = (ushort_t*)(w + R0 + 2 * MB8);
    ushort_t* wq_t   = (ushort_t*)(w + R0 + 3 * MB8);
    ushort_t* wv_t   = (ushort_t*)(w + R0 + 4 * MB8);
    ushort_t* wo_t   = (ushort_t*)(w + R0 + 5 * MB8);
    ushort_t* xb     = (ushort_t*)(w + R0 + 6 * MB8);  // 32 MiB; also y_head
    ushort_t* a_half = (ushort_t*)(w + R0);            // 64 MiB, written after all above die
    ushort_t* qb     = (ushort_t*)(w + R1);            // f16 32 MiB
    ushort_t* vb     = (ushort_t*)(w + R1 + 4 * MB8);  // f16 32 MiB
    float*    h_buf  = (float*)(w + R1);               // f32 64 MiB, after q/v die
    ushort_t* apad   = (ushort_t*)(w + R2);
    ushort_t* w1_t   = (ushort_t*)(w + R3);
    ushort_t* w2_t   = (ushort_t*)(w + R4);
    float*    beta   = (float*)(w + R5 + 0 * SCAN_SM);
    float*    parr   = (float*)(w + R5 + 1 * SCAN_SM);
    float*    carr   = (float*)(w + R5 + 2 * SCAN_SM);
    float*    csum   = (float*)(w + R5 + 3 * SCAN_SM);
    float*    cprf   = (float*)(w + R5 + 4 * SCAN_SM);
    ushort_t* mlp_in = apad;
    ushort_t* y_head = xb;

    // weight conversions
    conv_w_convert<<<(2048 * 2048) / 256, 256, 0, stream>>>(conv_w, wc0, wc1, wc2);
    transpose_to_f16<<<dim3(64, 64), dim3(32, 8), 0, stream>>>(wq, wq_t, 2048, 2048);
    transpose_to_f16<<<dim3(64, 64), dim3(32, 8), 0, stream>>>(wv, wv_t, 2048, 2048);
    transpose_to_f16<<<dim3(64, 64), dim3(32, 8), 0, stream>>>(wo, wo_t, 2048, 2048);
    transpose_to_f16<<<dim3(256, 64), dim3(32, 8), 0, stream>>>(w1, w1_t, 2048, 8192);
    transpose_to_f16<<<dim3(64, 256), dim3(32, 8), 0, stream>>>(w2, w2_t, 8192, 2048);

    // norm1 -> padded f16 (conv input / dt input)
    rmsnorm_kernel<<<MROWS, 256, 0, stream>>>(hidden, n1w, apad, 1);
    // dt path
    dt_kernel<<<MROWS, 256, 0, stream>>>(apad, w_dt, b_dt, dt_bias, beta);
    scan_prep<<<B_DIM * NHEADS, 256, 0, stream>>>(beta, A_log, parr, carr);

    // conv (3-shift GEMM) -> x f16
    gemm256<2, 3><<<dim3(8, 32), 512, 0, stream>>>(
        apad, wc0, wc1, wc2, conv_b, nullptr, nullptr, xb,
        MROWS, 2048, 2048, 2048, 2048);
    // q, v projections -> f16
    gemm256<5, 1><<<dim3(8, 32), 512, 0, stream>>>(
        xb, wq_t, wq_t, wq_t, nullptr, nullptr, nullptr, qb,
        MROWS, 2048, 2048, 2048, 2048);
    gemm256<5, 1><<<dim3(8, 32), 512, 0, stream>>>(
        xb, wv_t, wv_t, wv_t, nullptr, nullptr, nullptr, vb,
        MROWS, 2048, 2048, 2048, 2048);
    rope_f16<<<(MROWS * NHEADS * 64) / 256, 256, 0, stream>>>(qb, pos_ids);

    // delta-net scan -> y_head f16 (overwrites xb: conv-x dead after q/v)
    scan_partial<<<B_DIM * NHEADS * NCHUNK, 128, 0, stream>>>(carr, vb, csum);
    scan_combine<<<B_DIM * NHEADS, 128, 0, stream>>>(csum, cprf);
    scan_final<<<B_DIM * NHEADS * NCHUNK, 128, 0, stream>>>(carr, parr, vb, qb, cprf, y_head);

    // wo + residual -> h (overwrites qb/vb region: both dead)
    gemm256<3, 1><<<dim3(8, 32), 512, 0, stream>>>(
        y_head, wo_t, wo_t, wo_t, nullptr, hidden, h_buf, nullptr,
        MROWS, 2048, 2048, 2048, 2048);
    // norm2 -> mlp_in f16 (overwrites apad)
    rmsnorm_kernel<<<MROWS, 256, 0, stream>>>(h_buf, n2w, mlp_in, 0);

    // MLP in two INTER/2 halves to halve the intermediate buffer
    for (int ha = 0; ha < 2; ha++) {
        // silu(mlp_in @ w1_half) -> a_half f16
        gemm256<4, 1><<<dim3(16, 32), 512, 0, stream>>>(
            mlp_in, w1_t + (size_t)ha * 4096 * 2048, nullptr, nullptr,
            nullptr, nullptr, nullptr, a_half,
            MROWS, 4096, 2048, 2048, 2048);
        // out = (ha==0 ? h : out) + a_half @ w2_half
        gemm256<3, 1><<<dim3(8, 32), 512, 0, stream>>>(
            a_half, w2_t + (size_t)ha * 4096, nullptr, nullptr,
            nullptr, (ha == 0) ? h_buf : out, out, nullptr,
            MROWS, 2048, 4096, 4096, 8192);
    }
}